// Round 3
// baseline (126.811 us; speedup 1.0000x reference)
//
#include <hip/hip_runtime.h>

static constexpr int H = 2048;
static constexpr int W = 2048;
static constexpr int BLOCK = 256;
static constexpr int PXT = 8;                 // pixels per thread; one block = one row
static constexpr int NBLOCKS = H;             // 2048

__device__ __forceinline__ float fexp2(float x){ return __builtin_amdgcn_exp2f(x); }
__device__ __forceinline__ float flog2(float x){ return __builtin_amdgcn_logf(x); }
__device__ __forceinline__ float frcp (float x){ return __builtin_amdgcn_rcpf(x); }

// Loads 10 values: cols x0-1 .. x0+8 of one row (zero at image edge).
__device__ __forceinline__ void load_row(const float* __restrict__ p, int b,
                                         bool hasL, bool hasR, float v[10]) {
    const float4 a = *(const float4*)(p + b);
    const float4 c = *(const float4*)(p + b + 4);
    v[1]=a.x; v[2]=a.y; v[3]=a.z; v[4]=a.w;
    v[5]=c.x; v[6]=c.y; v[7]=c.z; v[8]=c.w;
    v[0] = hasL ? p[b-1]    : 0.f;
    v[9] = hasR ? p[b+PXT]  : 0.f;
}

// Per-pixel JS divergence over 3x3 Gaussian-weighted neighbor PDFs (sigma=1).
//   t = 0.5*log2(e)*d^2,  e = exp2(-t)  (so e = exp(-d^2/2))
//   sum e*d^2 = (2 ln2) * sum e*t
//   per-pixel: pacc = Sp*invGp + Sq*invGq + log2 Gp + log2 Gq + 2*sum m*log2 m
//   output = -ln2 * sum(pacc)
__global__ __launch_bounds__(BLOCK) void jsd_kernel(
    const float* __restrict__ A, const float* __restrict__ B,
    float* __restrict__ partial, unsigned int* __restrict__ counter,
    float* __restrict__ out)
{
    constexpr float S   = 0.84932180028801905f;   // sqrt(0.5*log2(e))
    constexpr float LN2 = 0.69314718055994531f;

    const int y    = blockIdx.x;
    const int x0   = threadIdx.x * PXT;
    const int base = y * W + x0;
    const bool hasL = (x0 > 0);
    const bool hasR = (x0 + PXT < W);

    float Av[3][10], Bv[3][10];
    load_row(A, base, hasL, hasR, Av[1]);
    load_row(B, base, hasL, hasR, Bv[1]);
    if (y > 0) {
        load_row(A, base - W, hasL, hasR, Av[0]);
        load_row(B, base - W, hasL, hasR, Bv[0]);
    } else {
        #pragma unroll
        for (int c = 0; c < 10; ++c) { Av[0][c] = 0.f; Bv[0][c] = 0.f; }
    }
    if (y < H - 1) {
        load_row(A, base + W, hasL, hasR, Av[2]);
        load_row(B, base + W, hasL, hasR, Bv[2]);
    } else {
        #pragma unroll
        for (int c = 0; c < 10; ++c) { Av[2][c] = 0.f; Bv[2][c] = 0.f; }
    }

    // horizontal pair exps for the middle row, shared between adjacent pixels
    float heA[9], htA[9], heB[9], htB[9];   // e  and  e*t
    #pragma unroll
    for (int c = 0; c < 9; ++c) {
        float d, u, t, e;
        d = Av[1][c+1] - Av[1][c]; u = d*S; t = u*u; e = fexp2(-t);
        heA[c] = e; htA[c] = e*t;
        d = Bv[1][c+1] - Bv[1][c]; u = d*S; t = u*u; e = fexp2(-t);
        heB[c] = e; htB[c] = e*t;
    }

    float pacc = 0.f;
    #pragma unroll
    for (int j = 0; j < PXT; ++j) {
        const float ca = Av[1][j+1];
        const float cb = Bv[1][j+1];

        float Gp = 1.f + heA[j] + heA[j+1];
        float Sp = htA[j] + htA[j+1];
        float Gq = 1.f + heB[j] + heB[j+1];
        float Sq = htB[j] + htB[j+1];

        float veA[6], veB[6];
        #pragma unroll
        for (int r = 0; r < 2; ++r) {
            const int rr = r ? 2 : 0;
            #pragma unroll
            for (int c2 = 0; c2 < 3; ++c2) {
                float d, u, t, e;
                d = Av[rr][j+c2] - ca; u = d*S; t = u*u; e = fexp2(-t);
                veA[r*3+c2] = e; Gp += e; Sp = fmaf(e, t, Sp);
                d = Bv[rr][j+c2] - cb; u = d*S; t = u*u; e = fexp2(-t);
                veB[r*3+c2] = e; Gq += e; Sq = fmaf(e, t, Sq);
            }
        }

        const float ip = frcp(Gp), iq = frcp(Gq);
        const float hp = 0.5f*ip,  hq = 0.5f*iq;

        float m = hp + hq;                         // center tap (g=1 both)
        float mll = m * flog2(m);
        m = fmaf(heA[j],   hp, heB[j]  *hq); mll = fmaf(m, flog2(m), mll);
        m = fmaf(heA[j+1], hp, heB[j+1]*hq); mll = fmaf(m, flog2(m), mll);
        #pragma unroll
        for (int k = 0; k < 6; ++k) {
            m = fmaf(veA[k], hp, veB[k]*hq);
            mll = fmaf(m, flog2(m), mll);
        }

        pacc += fmaf(Sp, ip, Sq*iq) + flog2(Gp) + flog2(Gq) + 2.f*mll;
    }

    // wave64 reduce, cross-wave via LDS
    #pragma unroll
    for (int off = 32; off > 0; off >>= 1)
        pacc += __shfl_down(pacc, off, 64);

    __shared__ float wsum[BLOCK/64];
    __shared__ int isLast;
    const int lane = threadIdx.x & 63;
    const int wid  = threadIdx.x >> 6;
    if (lane == 0) wsum[wid] = pacc;
    __syncthreads();
    if (threadIdx.x == 0) {
        const float bsum = wsum[0] + wsum[1] + wsum[2] + wsum[3];
        __hip_atomic_store(&partial[blockIdx.x], bsum,
                           __ATOMIC_RELEASE, __HIP_MEMORY_SCOPE_AGENT);
        const unsigned old = __hip_atomic_fetch_add(counter, 1u,
                           __ATOMIC_ACQ_REL, __HIP_MEMORY_SCOPE_AGENT);
        isLast = (old == (unsigned)(NBLOCKS - 1));
    }
    __syncthreads();

    if (isLast) {   // block-uniform: deterministic final sum (fixed order)
        float s = 0.f;
        #pragma unroll
        for (int i = 0; i < NBLOCKS / BLOCK; ++i)
            s += __hip_atomic_load(&partial[i*BLOCK + threadIdx.x],
                                   __ATOMIC_ACQUIRE, __HIP_MEMORY_SCOPE_AGENT);
        #pragma unroll
        for (int off = 32; off > 0; off >>= 1)
            s += __shfl_down(s, off, 64);
        if (lane == 0) wsum[wid] = s;
        __syncthreads();
        if (threadIdx.x == 0)
            out[0] = -LN2 * (wsum[0] + wsum[1] + wsum[2] + wsum[3]);
    }
}

extern "C" void kernel_launch(void* const* d_in, const int* in_sizes, int n_in,
                              void* d_out, int out_size, void* d_ws, size_t ws_size,
                              hipStream_t stream) {
    const float* A = (const float*)d_in[0];
    const float* B = (const float*)d_in[1];
    float* out = (float*)d_out;
    float* partial = (float*)d_ws;                       // NBLOCKS floats
    unsigned int* counter = (unsigned int*)d_ws + NBLOCKS;

    hipMemsetAsync(counter, 0, sizeof(unsigned int), stream);
    jsd_kernel<<<NBLOCKS, BLOCK, 0, stream>>>(A, B, partial, counter, out);
}